// Round 6
// baseline (146.895 us; speedup 1.0000x reference)
//
#include <hip/hip_runtime.h>
#include <math.h>

#define SEQ   1024
#define DQ    256
#define DVD   512
#define NHH   16          // B*NH
#define EPSF  1e-6f
#define INV_SQRT_D 0.0625f   // 1/sqrt(256)

typedef __attribute__((ext_vector_type(8)))  short short8v;
typedef __attribute__((ext_vector_type(16))) float f32x16;

// ---- workspace layout (float offsets) ----
#define WS_FG    0                        // [16][1024]
#define WS_IG    (NHH*SEQ)                // [16][1024]
#define WS_ELIM  (2*NHH*SEQ)              // [16][1024]  exp(-m_t)
#define WS_HDEN  (3*NHH*SEQ)              // [16][1024]
#define WS_AT    (4*NHH*SEQ)              // [16][1024]  a_t = F_t - m_t
#define WS_CS    (5*NHH*SEQ)              // [16][1024]  c_s = i_s - F_s
#define WS_UT    (6*NHH*SEQ)              // [16][1024]  u_t (final C/n weight)
#define WS_AC    (7*NHH*SEQ)              // [16][16]
#define WS_BVEC  (WS_AC + NHH*16)         // [16][16][256]
#define WS_NST   (WS_BVEC + NHH*16*DQ)    // [16][16][256]
#define WS_SMALL_FLOATS (WS_NST + NHH*16*DQ)

#define QBF_OFF  ((size_t)WS_SMALL_FLOATS * 4)             // bytes (16-aligned)
#define KBF_OFF  (QBF_OFF + (size_t)NHH*SEQ*DQ*2)
#define VTB_OFF  (KBF_OFF + (size_t)NHH*SEQ*DQ*2)          // vt2 blocked layout
#define KUT_OFF  (VTB_OFF + (size_t)NHH*DVD*SEQ*2)

__device__ __forceinline__ unsigned short f2bf(float f) {
  unsigned int u = __float_as_uint(f);
  return (unsigned short)((u + 0x7fffu + ((u >> 16) & 1u)) >> 16);
}

__device__ __forceinline__ void gl_lds16(const void* g, void* l) {
  __builtin_amdgcn_global_load_lds(
      (const __attribute__((address_space(1))) unsigned int*)g,
      (__attribute__((address_space(3))) unsigned int*)l, 16, 0, 0);
}

// ============================================================
// Gates: wave-shfl scans. Emits fg, ig, exp(-m), a_t, c_s, u_t, AC, m_out.
// ============================================================
__global__ __launch_bounds__(1024) void gates_kernel(
    const float* __restrict__ ipre, const float* __restrict__ fpre,
    float* __restrict__ ws, float* __restrict__ m_out) {
  const int hh = blockIdx.x;
  const int t  = threadIdx.x;
  const int lane = t & 63, wid = t >> 6;   // 16 waves
  __shared__ float Fs[SEQ];
  __shared__ float Ms[SEQ];
  __shared__ float wsum[16];
  __shared__ float wmax[16];

  const float fp = fpre[hh*SEQ + t];
  const float ip = ipre[hh*SEQ + t];
  const float flog = fminf(fp, 0.f) - log1pf(expf(-fabsf(fp)));

  float v = flog;
  #pragma unroll
  for (int off = 1; off < 64; off <<= 1) {
    float o = __shfl_up(v, off, 64);
    if (lane >= off) v += o;
  }
  if (lane == 63) wsum[wid] = v;
  __syncthreads();
  float woff = 0.f;
  #pragma unroll
  for (int i = 0; i < 16; ++i) { float s = wsum[i]; if (i < wid) woff += s; }
  const float F = v + woff;
  Fs[t] = F;

  float zm = ip - F;
  #pragma unroll
  for (int off = 1; off < 64; off <<= 1) {
    float o = __shfl_up(zm, off, 64);
    if (lane >= off) zm = fmaxf(zm, o);
  }
  if (lane == 63) wmax[wid] = zm;
  __syncthreads();
  float zoff = -INFINITY;
  #pragma unroll
  for (int i = 0; i < 16; ++i) { float s = wmax[i]; if (i < wid) zoff = fmaxf(zoff, s); }
  const float zfull = fmaxf(zm, zoff);
  const float m_t = F + fmaxf(zfull, 0.f);
  Ms[t] = m_t;
  __syncthreads();

  const float m_prev = (t == 0) ? 0.f : Ms[t - 1];
  const float F_end = Fs[SEQ-1], m_end = Ms[SEQ-1];

  ws[WS_FG   + hh*SEQ + t] = expf(flog + m_prev - m_t);
  ws[WS_IG   + hh*SEQ + t] = expf(ip - m_t);
  ws[WS_ELIM + hh*SEQ + t] = expf(-m_t);
  ws[WS_AT   + hh*SEQ + t] = F - m_t;
  ws[WS_CS   + hh*SEQ + t] = ip - F;
  ws[WS_UT   + hh*SEQ + t] = expf(F_end - F + ip - m_end);
  if (t == SEQ - 1) m_out[hh] = m_t;
  if ((t & 63) == 63) {
    const int c = t >> 6;
    const float Fprev  = (c == 0) ? 0.f : Fs[t - 64];
    const float mprevc = (c == 0) ? 0.f : Ms[t - 64];
    ws[WS_AC + hh*16 + c] = expf((F - Fprev) + (mprevc - m_t));
  }
}

// ============================================================
// Role-fused prep kernel.
//  blocks [0,256): (head,chunk64) — read k ONCE: k_bf cast, bvec scan,
//                  kut = bf16(u_t * k) transposed [d][t].
//  blocks [256,768): (head, 32-row t-group) — v -> vt2 blocked transpose:
//                  vt2[h][c:16][vpair:256][ (v&1)*64 + (t&63) ]
// ============================================================
__global__ __launch_bounds__(256) void prep_kernel(
    const float* __restrict__ kin, const float* __restrict__ vin,
    float* __restrict__ ws,
    unsigned short* __restrict__ k_bf, unsigned short* __restrict__ vt2,
    unsigned short* __restrict__ kut) {
  __shared__ float lk[64][257];
  const int b = blockIdx.x;
  if (b < 256) {
    const int hh = b >> 4, c = b & 15;
    const int d = threadIdx.x;
    const int tbase = hh*SEQ + c*64;
    const size_t base = (size_t)tbase * DQ;
    #pragma unroll 4
    for (int tt = 0; tt < 64; ++tt) {
      const float val = kin[base + (size_t)tt*DQ + d];
      lk[tt][d] = val;
      k_bf[base + (size_t)tt*DQ + d] = f2bf(val);
    }
    __syncthreads();
    const float* fg = ws + WS_FG + tbase;
    const float* ig = ws + WS_IG + tbase;
    float nb = 0.f;
    #pragma unroll 8
    for (int tt = 0; tt < 64; ++tt) nb = fg[tt]*nb + ig[tt]*lk[tt][d];
    ws[WS_BVEC + (hh*16 + c)*DQ + d] = nb;
    const float* u = ws + WS_UT + tbase;
    #pragma unroll
    for (int g = 0; g < 8; ++g) {
      short8v pk;
      #pragma unroll
      for (int j = 0; j < 8; ++j) {
        const int tt = g*8 + j;
        pk[j] = (short)f2bf(u[tt] * lk[tt][d]);
      }
      *(short8v*)(kut + ((size_t)(hh*DQ + d))*SEQ + c*64 + g*8) = pk;
    }
  } else {
    const int b2 = b - 256;            // 0..511
    const int hh = b2 >> 5, tg = b2 & 31;
    const int tx = threadIdx.x & 31, ty = threadIdx.x >> 5;
    float (*tile)[33] = (float(*)[33])lk;
    const int c = tg >> 1;
    const int s32 = (tg & 1) * 32;     // t&63 base
    for (int vt = 0; vt < 16; ++vt) {
      #pragma unroll
      for (int i = 0; i < 4; ++i)
        tile[ty + 8*i][tx] =
            vin[((size_t)(hh*SEQ + tg*32 + ty + 8*i))*DVD + vt*32 + tx];
      __syncthreads();
      #pragma unroll
      for (int i = 0; i < 4; ++i) {
        const int vv = vt*32 + ty + 8*i;
        vt2[((size_t)((hh*16 + c)*256 + (vv>>1)))*128 + (vv&1)*64 + s32 + tx] =
            f2bf(tile[tx][ty + 8*i]);
      }
      __syncthreads();
    }
  }
}

// ============================================================
// nscan: 16-chunk affine scan of n (exact fp32)
// ============================================================
__global__ __launch_bounds__(256) void nscan_kernel(
    float* __restrict__ ws, float* __restrict__ n_out) {
  const int hh = blockIdx.x;
  const int d  = threadIdx.x;
  float n = 0.f;
  for (int c = 0; c < 16; ++c) {
    ws[WS_NST + (hh*16 + c)*DQ + d] = n;
    n = ws[WS_AC + hh*16 + c]*n + ws[WS_BVEC + (hh*16 + c)*DQ + d];
  }
  n_out[hh*DQ + d] = n;
}

// ============================================================
// hden (exact fp32) + fused q_bf cast (q/16 -> bf16)
// ============================================================
__global__ __launch_bounds__(256) void hden_kernel(
    const float* __restrict__ kin, const float* __restrict__ qin,
    float* __restrict__ ws, unsigned short* __restrict__ q_bf) {
  const int hh = blockIdx.x >> 4;
  const int c  = blockIdx.x & 15;
  const int d  = threadIdx.x;
  __shared__ float pbuf[64][DQ];
  float n = ws[WS_NST + (hh*16 + c)*DQ + d];
  const int tbase = hh*SEQ + c*64;
  const size_t base = (size_t)tbase * DQ;
  #pragma unroll 4
  for (int tt = 0; tt < 64; ++tt) {
    const float fg = ws[WS_FG + tbase + tt];
    const float ig = ws[WS_IG + tbase + tt];
    n = fg*n + ig*kin[base + (size_t)tt*DQ + d];
    const float qv = qin[base + (size_t)tt*DQ + d];
    q_bf[base + (size_t)tt*DQ + d] = f2bf(qv * INV_SQRT_D);
    pbuf[tt][d] = n * qv;
  }
  __syncthreads();
  if (d < 64) {
    float s = 0.f;
    #pragma unroll 8
    for (int jj = 0; jj < DQ; ++jj) s += pbuf[d][(d + jj) & (DQ - 1)];
    const float qn = s * INV_SQRT_D;
    const float hd = fmaxf(fabsf(qn), ws[WS_ELIM + tbase + d]) + EPSF;
    ws[WS_HDEN + tbase + d] = hd;
  }
}

// ============================================================
// Attention main kernel.
// Grid 256 = 16h x pair(p,7-p of 128-row q-tiles) x 4 v-quarters.
// 8 waves: w<4 -> long tile, w>=4 -> short tile; wq = tsub (S) / vsub (PV).
// chunk=64 s. K dbuf 2x32K (512B rows, 5-bit XOR), V dbuf 2x16K and
// P 2x16K pair-packed 256B rows with 4-bit slot16 XOR -> <=2-way conflicts.
// stage(j+2) issued post-PV; top-of-loop vmcnt(6) keeps 1 chunk in flight.
// ============================================================
__global__ __launch_bounds__(512, 2) void attn_kernel(
    const unsigned short* __restrict__ q_bf,
    const unsigned short* __restrict__ k_bf,
    const unsigned short* __restrict__ vt2,
    const float* __restrict__ ws,
    float* __restrict__ h_out) {
  const int blk = blockIdx.x;
  const int xcd = blk & 7, slot = blk >> 3;
  const int hh  = xcd*2 + (slot & 1);     // 2 heads per XCD
  const int rest = slot >> 1;             // 0..15
  const int p   = rest & 3;
  const int vq  = rest >> 2;              // 0..3 (128-wide v quarter)
  const int qL = 7 - p, qS = p;
  const int nchL = 16 - 2*p, nchS = 2*p + 2;

  const int tid = threadIdx.x;
  const int w = tid >> 6, lane = tid & 63, l31 = lane & 31, hl = lane >> 5;
  const int tileSel = w >> 2;             // 0: long, 1: short
  const int wq = w & 3;                   // tsub (S-phase) / vsub (PV)
  const int myq  = tileSel ? qS : qL;
  const int nchW = tileSel ? nchS : nchL;

  __shared__ unsigned short Kb[2][64*256];   // 2 x 32 KB  [s][d]
  __shared__ unsigned short Vb[2][64*128];   // 2 x 16 KB  [vpair][slot16]
  __shared__ unsigned short Pb[2][64*128];   // 2 tiles x 16 KB [tpair][slot16]

  const float* c_g  = ws + WS_CS   + hh*SEQ;
  const float* hd_g = ws + WS_HDEN + hh*SEQ;

  const int tq = myq*128 + wq*32 + l31;      // lane's global t (S-phase col)
  const float a_t = ws[WS_AT + hh*SEQ + tq];
  const unsigned short* qp = q_bf + ((size_t)(hh*SEQ + tq))*DQ + hl*8;
  short8v qfrag[16];
  #pragma unroll
  for (int d = 0; d < 16; ++d) qfrag[d] = *(const short8v*)(qp + d*16);

  f32x16 acc[4] = {};

  auto stageK = [&](int j) {
    const int buf = j & 1; const int s0 = j*64;
    #pragma unroll
    for (int p4 = 0; p4 < 4; ++p4) {
      const int u = p4*512 + tid;
      const int row = u >> 5, sl = u & 31;
      const unsigned short* src = k_bf +
          ((size_t)(hh*SEQ + s0 + row))*DQ + ((sl ^ (row & 31))*8);
      gl_lds16(src, (char*)&Kb[buf][0] + (p4*8 + w)*1024);
    }
  };
  auto stageV = [&](int j) {
    const int buf = j & 1;
    const unsigned short* basep = vt2 +
        ((size_t)((hh*16 + j)*256 + vq*64))*128;
    #pragma unroll
    for (int p2 = 0; p2 < 2; ++p2) {
      const int u = p2*512 + tid;
      const int vpl = u >> 4, s16 = u & 15;
      const unsigned short* src = basep + (size_t)vpl*128 + ((s16 ^ (vpl & 15))*8);
      gl_lds16(src, (char*)&Vb[buf][0] + (p2*8 + w)*1024);
    }
  };

  const int tl_s = wq*32 + l31;            // lane's local t in its tile
  const int tp_s = tl_s >> 1, th_s = tl_s & 1;

  stageK(0); stageV(0);
  if (nchL > 1) { stageK(1); stageV(1); }

  for (int j = 0; j < nchL; ++j) {
    const int buf = j & 1;
    if (j + 1 < nchL) { asm volatile("s_waitcnt vmcnt(6)" ::: "memory"); }
    else              { asm volatile("s_waitcnt vmcnt(0)" ::: "memory"); }
    __builtin_amdgcn_sched_barrier(0);
    __builtin_amdgcn_s_barrier();
    __builtin_amdgcn_sched_barrier(0);

    const bool act = (j < nchW);
    if (act) {
      // ---- S-phase: two independent 32s x 32t sacc chains ----
      f32x16 sa0 = {}, sa1 = {};
      const int sr0 = l31, sr1 = 32 + l31;
      __builtin_amdgcn_s_setprio(1);
      #pragma unroll
      for (int d = 0; d < 16; ++d) {
        short8v k0 = *(const short8v*)&Kb[buf][sr0*256 + (((d*2+hl) ^ (sr0 & 31))*8)];
        short8v k1 = *(const short8v*)&Kb[buf][sr1*256 + (((d*2+hl) ^ (sr1 & 31))*8)];
        sa0 = __builtin_amdgcn_mfma_f32_32x32x16_bf16(k0, qfrag[d], sa0, 0, 0, 0);
        sa1 = __builtin_amdgcn_mfma_f32_32x32x16_bf16(k1, qfrag[d], sa1, 0, 0, 0);
      }
      __builtin_amdgcn_s_setprio(0);
      // ---- weight + mask + pack -> Pb (slot16-swizzled) ----
      #pragma unroll
      for (int sb = 0; sb < 2; ++sb) {
        const f32x16& sa = sb ? sa1 : sa0;
        #pragma unroll
        for (int i = 0; i < 8; ++i) {
          const int r0 = 2*i;
          const int sl = sb*32 + (r0 & 3) + 8*(r0 >> 2) + 4*hl;
          const int sg = j*64 + sl;
          const float cc0 = c_g[sg], cc1 = c_g[sg + 1];
          const float p0 = (sg     <= tq) ? __expf(a_t + cc0)*sa[r0]   : 0.f;
          const float p1 = (sg + 1 <= tq) ? __expf(a_t + cc1)*sa[r0+1] : 0.f;
          unsigned int pk;
          asm volatile("v_cvt_pk_bf16_f32 %0, %1, %2" : "=v"(pk) : "v"(p0), "v"(p1));
          const int s16 = ((th_s << 3) | (sl >> 3)) ^ (tp_s & 15);
          *(unsigned int*)&Pb[tileSel][tp_s*128 + s16*8 + (sl & 7)] = pk;
        }
      }
    }

    asm volatile("s_waitcnt lgkmcnt(0)" ::: "memory");
    __builtin_amdgcn_sched_barrier(0);
    __builtin_amdgcn_s_barrier();
    __builtin_amdgcn_sched_barrier(0);

    if (act) {
      // ---- PV: acc[ts] += P[ts-rows][s] * V[s][v]; vb reused 4x ----
      __builtin_amdgcn_s_setprio(1);
      #pragma unroll
      for (int kap = 0; kap < 4; ++kap) {
        const int vl_ = wq*32 + l31;
        const int vp = vl_ >> 1;
        const int sv = (((vl_ & 1) << 3) | (kap*2 + hl)) ^ (vp & 15);
        short8v vb = *(const short8v*)&Vb[buf][vp*128 + sv*8];
        #pragma unroll
        for (int ts = 0; ts < 4; ++ts) {
          const int tl = ts*32 + l31;
          const int tp = tl >> 1;
          const int sp = (((tl & 1) << 3) | (kap*2 + hl)) ^ (tp & 15);
          short8v pa = *(const short8v*)&Pb[tileSel][tp*128 + sp*8];
          acc[ts] = __builtin_amdgcn_mfma_f32_32x32x16_bf16(pa, vb, acc[ts], 0, 0, 0);
        }
      }
      __builtin_amdgcn_s_setprio(0);
    }

    __builtin_amdgcn_s_barrier();        // V(j)/P fully consumed
    __builtin_amdgcn_sched_barrier(0);
    if (j + 2 < nchL) { stageK(j+2); stageV(j+2); }
  }

  // ---- epilogue: exact denominator, write h ----
  #pragma unroll
  for (int ts = 0; ts < 4; ++ts) {
    #pragma unroll
    for (int r = 0; r < 16; ++r) {
      const int tl = ts*32 + (r & 3) + 8*(r >> 2) + 4*hl;
      const int tg = myq*128 + tl;
      const float inv = 1.0f / hd_g[tg];
      h_out[((size_t)(hh*SEQ + tg))*DVD + vq*128 + wq*32 + l31] = acc[ts][r]*inv;
    }
  }
}

// ============================================================
// C GEMM: C[h][d][v] = sum_t kut[h][d][t] * vt2[h][v][t]
// ============================================================
__global__ __launch_bounds__(256, 2) void cgemm_kernel(
    const unsigned short* __restrict__ kut,
    const unsigned short* __restrict__ vt2,
    float* __restrict__ C_out) {
  const int b = blockIdx.x;       // 16h x 2mt x 8nt
  const int hh = b >> 4;
  const int mt = (b >> 3) & 1;
  const int nt = b & 7;
  const int tid = threadIdx.x;
  const int w = tid >> 6, lane = tid & 63, l31 = lane & 31, hl = lane >> 5;
  const int mr = w >> 1;
  const int nc = w & 1;

  __shared__ unsigned short Alds[128*64];  // 16 KB, [d][t] rows 128B
  __shared__ unsigned short Blds[32*128];  //  8 KB, [vpair][slot16] rows 256B

  f32x16 acc0 = {}, acc1 = {};
  for (int c = 0; c < 16; ++c) {
    const int t0 = c*64;
    #pragma unroll
    for (int p = 0; p < 4; ++p) {
      int u = p*256 + tid; int row = u >> 3, slot = u & 7;
      const unsigned short* src = kut +
          ((size_t)(hh*DQ + mt*128 + row))*SEQ + t0 + ((slot ^ (row & 7))*8);
      gl_lds16(src, (char*)Alds + (p*4 + w)*1024);
    }
    {
      const unsigned short* basep = vt2 +
          ((size_t)((hh*16 + c)*256 + nt*32))*128;
      #pragma unroll
      for (int p = 0; p < 2; ++p) {
        int u = p*256 + tid; int r = u >> 4, s16 = u & 15;
        const unsigned short* src = basep + (size_t)r*128 + ((s16 ^ (r & 15))*8);
        gl_lds16(src, (char*)Blds + (p*4 + w)*1024);
      }
    }
    __syncthreads();
    #pragma unroll
    for (int ks = 0; ks < 4; ++ks) {
      const int vl_ = nc*32 + l31;
      const int vp = vl_ >> 1;
      const int s16 = (((vl_ & 1) << 3) | (ks*2 + hl)) ^ (vp & 15);
      short8v bf_ = *(const short8v*)&Blds[vp*128 + s16*8];
      const int ar0 = mr*64 + l31, ar1 = ar0 + 32;
      short8v a0 = *(const short8v*)&Alds[ar0*64 + (((ks*2 + hl) ^ (ar0 & 7))*8)];
      short8v a1 = *(const short8v*)&Alds[ar1*64 + (((ks*2 + hl) ^ (ar1 & 7))*8)];
      acc0 = __builtin_amdgcn_mfma_f32_32x32x16_bf16(a0, bf_, acc0, 0, 0, 0);
      acc1 = __builtin_amdgcn_mfma_f32_32x32x16_bf16(a1, bf_, acc1, 0, 0, 0);
    }
    __syncthreads();
  }
  #pragma unroll
  for (int r = 0; r < 16; ++r) {
    const int dl = (r & 3) + 8*(r >> 2) + 4*hl;
    const int d0 = mt*128 + mr*64 + dl;
    const size_t ob = ((size_t)(hh*DQ + d0))*DVD + nt*64 + nc*32 + l31;
    C_out[ob]            = acc0[r];
    C_out[ob + 32*DVD]   = acc1[r];
  }
}

// ============================================================
extern "C" void kernel_launch(void* const* d_in, const int* in_sizes, int n_in,
                              void* d_out, int out_size, void* d_ws, size_t ws_size,
                              hipStream_t stream) {
  const float* q  = (const float*)d_in[0];
  const float* k  = (const float*)d_in[1];
  const float* v  = (const float*)d_in[2];
  const float* ip = (const float*)d_in[3];
  const float* fp = (const float*)d_in[4];

  float* h_out = (float*)d_out;                       // [16][1024][512]
  float* C_out = h_out + (size_t)NHH*SEQ*DVD;         // [16][256][512]
  float* n_out = C_out + (size_t)NHH*DQ*DVD;          // [16][256]
  float* m_out = n_out + NHH*DQ;                      // [16]
  float* ws    = (float*)d_ws;

  unsigned short* q_bf  = (unsigned short*)((char*)d_ws + QBF_OFF);
  unsigned short* k_bf  = (unsigned short*)((char*)d_ws + KBF_OFF);
  unsigned short* vt2   = (unsigned short*)((char*)d_ws + VTB_OFF);
  unsigned short* kut   = (unsigned short*)((char*)d_ws + KUT_OFF);

  gates_kernel<<<NHH, 1024, 0, stream>>>(ip, fp, ws, m_out);
  prep_kernel<<<768, 256, 0, stream>>>(k, v, ws, k_bf, vt2, kut);
  nscan_kernel<<<NHH, 256, 0, stream>>>(ws, n_out);
  hden_kernel<<<NHH*16, 256, 0, stream>>>(k, q, ws, q_bf);
  attn_kernel<<<256, 512, 0, stream>>>(q_bf, k_bf, vt2, ws, h_out);
  cgemm_kernel<<<256, 256, 0, stream>>>(kut, vt2, C_out);
}